// Round 2
// baseline (1720.831 us; speedup 1.0000x reference)
//
#include <hip/hip_runtime.h>
#include <hip/hip_bf16.h>
#include <stdint.h>

// SelfAttention: hs[1,2048,6144] fp32; Wq/Wk/Wv[6144,6144], bq/bk/bv[6144] fp32.
// out[2048,6144] fp32 = softmax((hs Wq + bq)(hs Wk + bk)^T / sqrt(96)) (hs Wv + bv), 64 heads x 96.
// Strategy: bf16 MFMA everywhere (error budget ~2e-4 << 1.46e-3 threshold).
//   K1: QKV GEMM 128x128x64 tile, reg-staged fp32->bf16, W transposed into LDS.
//       Outputs Q,K as [h][s][d] bf16 and V as [h][d][s] bf16 (pre-transposed for PV).
//   K2: flash attention, 4 waves x 16 q-rows, 64-key tiles, swapped QK^T (S^T layout
//       makes softmax state lane-local), P through LDS, PV with contiguous Vt reads.

#define NH  64
#define DHD 96
#define DM  6144
#define SEQ 2048

typedef __attribute__((ext_vector_type(4))) float f4;
typedef __attribute__((ext_vector_type(4))) float f32x4;
typedef __attribute__((ext_vector_type(8))) short bf16x8;
typedef __attribute__((ext_vector_type(4))) short bf16x4;

static __device__ __forceinline__ short f2bf(float f) {
  unsigned int u = __builtin_bit_cast(unsigned int, f);
  u = (u + 0x7fffu + ((u >> 16) & 1u)) >> 16;   // RNE
  return (short)u;
}

// ---------------------------------------------------------------- QKV GEMM
// grid (48 n-tiles, 16 m-tiles, 3 weights), 256 threads (4 waves, 2x2 of 64x64).
// LDS: A[128][72] bf16 (m-major, k-contig), Bt[128][72] bf16 (n-major, k-contig).
// Pitch 72 bf16 = 36 dwords -> 16-lane frag reads hit 8 distinct bank groups (2-way, free).
__global__ __launch_bounds__(256)
void qkv_gemm(const float* __restrict__ hs,
              const float* __restrict__ Wq, const float* __restrict__ bq,
              const float* __restrict__ Wk, const float* __restrict__ bk,
              const float* __restrict__ Wv, const float* __restrict__ bv,
              short* __restrict__ Qo, short* __restrict__ Ko, short* __restrict__ Vto)
{
  const int z = blockIdx.z;
  const float* __restrict__ Wp = (z == 0) ? Wq : ((z == 1) ? Wk : Wv);
  const float* __restrict__ bp = (z == 0) ? bq : ((z == 1) ? bk : bv);

  const int tid  = threadIdx.x;
  const int lane = tid & 63;
  const int w    = tid >> 6;
  const int wr   = w >> 1, wc = w & 1;          // 2x2 wave grid, 64x64 each
  const int g    = lane >> 4, c = lane & 15;
  const int m0   = blockIdx.y * 128;
  const int n0   = blockIdx.x * 128;

  __shared__ short Al[128 * 72];
  __shared__ short Bl[128 * 72];

  f32x4 acc[4][4];
#pragma unroll
  for (int i = 0; i < 4; ++i)
#pragma unroll
    for (int j = 0; j < 4; ++j) acc[i][j] = (f32x4)0.f;

  const int nb  = tid & 31;   // B staging: 4-col group
  const int kb8 = tid >> 5;   // B staging: 8-row (k) group

  f4 areg[8];
  f4 breg[8];

  // prologue: load k-tile 0 into regs
  {
#pragma unroll
    for (int i = 0; i < 4; ++i) {
      int o = tid * 32 + i * 8192;              // byte offset in 128x64xfp32 tile
      int row = o >> 8, colf = (o & 255) >> 2;
      const float* p = hs + (size_t)(m0 + row) * DM + colf;
      areg[2*i]   = *(const f4*)p;
      areg[2*i+1] = *(const f4*)(p + 4);
    }
#pragma unroll
    for (int kk = 0; kk < 8; ++kk)
      breg[kk] = *(const f4*)(Wp + (size_t)(kb8*8 + kk) * DM + n0 + nb*4);
  }

  for (int kt = 0; kt < DM/64; ++kt) {
    // staged regs -> LDS (convert to bf16; B transposed to [n][k])
#pragma unroll
    for (int i = 0; i < 4; ++i) {
      int o = tid * 32 + i * 8192;
      int row = o >> 8, colf = (o & 255) >> 2;
      bf16x8 v;
      v[0]=f2bf(areg[2*i][0]);   v[1]=f2bf(areg[2*i][1]);
      v[2]=f2bf(areg[2*i][2]);   v[3]=f2bf(areg[2*i][3]);
      v[4]=f2bf(areg[2*i+1][0]); v[5]=f2bf(areg[2*i+1][1]);
      v[6]=f2bf(areg[2*i+1][2]); v[7]=f2bf(areg[2*i+1][3]);
      *(bf16x8*)&Al[row * 72 + colf] = v;
    }
#pragma unroll
    for (int nn = 0; nn < 4; ++nn) {
      bf16x8 v;
#pragma unroll
      for (int kk = 0; kk < 8; ++kk) v[kk] = f2bf(breg[kk][nn]);
      *(bf16x8*)&Bl[(nb*4 + nn) * 72 + kb8*8] = v;
    }
    __syncthreads();

    // prefetch next k-tile into regs (hides HBM latency under MFMA below)
    if (kt + 1 < DM/64) {
      const int k0 = (kt + 1) * 64;
#pragma unroll
      for (int i = 0; i < 4; ++i) {
        int o = tid * 32 + i * 8192;
        int row = o >> 8, colf = (o & 255) >> 2;
        const float* p = hs + (size_t)(m0 + row) * DM + k0 + colf;
        areg[2*i]   = *(const f4*)p;
        areg[2*i+1] = *(const f4*)(p + 4);
      }
#pragma unroll
      for (int kk = 0; kk < 8; ++kk)
        breg[kk] = *(const f4*)(Wp + (size_t)(k0 + kb8*8 + kk) * DM + n0 + nb*4);
    }

    // compute: 2 k-halves x 4x4 fragments
#pragma unroll
    for (int kh = 0; kh < 2; ++kh) {
      bf16x8 af[4], bfr[4];
#pragma unroll
      for (int i = 0; i < 4; ++i)
        af[i]  = *(bf16x8*)&Al[(wr*64 + i*16 + c) * 72 + kh*32 + g*8];
#pragma unroll
      for (int j = 0; j < 4; ++j)
        bfr[j] = *(bf16x8*)&Bl[(wc*64 + j*16 + c) * 72 + kh*32 + g*8];
#pragma unroll
      for (int i = 0; i < 4; ++i)
#pragma unroll
        for (int j = 0; j < 4; ++j)
          acc[i][j] = __builtin_amdgcn_mfma_f32_16x16x32_bf16(af[i], bfr[j], acc[i][j], 0, 0, 0);
    }
    __syncthreads();
  }

  // epilogue: +bias, cast bf16.  C/D layout: col = lane&15, row = (lane>>4)*4 + reg.
  if (z < 2) {
    short* __restrict__ outp = (z == 0) ? Qo : Ko;    // [h][s][d]
#pragma unroll
    for (int j = 0; j < 4; ++j) {
      int n = n0 + wc*64 + j*16 + c;
      int hh = n / DHD, d = n - hh * DHD;
      float bias = bp[n];
      short* ob = outp + (size_t)hh * SEQ * DHD + d;
#pragma unroll
      for (int i = 0; i < 4; ++i) {
        int srow = m0 + wr*64 + i*16 + g*4;
#pragma unroll
        for (int r = 0; r < 4; ++r)
          ob[(size_t)(srow + r) * DHD] = f2bf(acc[i][j][r] + bias);
      }
    }
  } else {
    // V transposed: Vt[h][d][s]; 4 consecutive rows (s) per fragment reg -> 8B stores
#pragma unroll
    for (int j = 0; j < 4; ++j) {
      int n = n0 + wc*64 + j*16 + c;
      int hh = n / DHD, d = n - hh * DHD;
      float bias = bp[n];
      short* ob = Vto + ((size_t)hh * DHD + d) * SEQ;
#pragma unroll
      for (int i = 0; i < 4; ++i) {
        int srow = m0 + wr*64 + i*16 + g*4;
        bf16x4 v;
        v[0]=f2bf(acc[i][j][0]+bias); v[1]=f2bf(acc[i][j][1]+bias);
        v[2]=f2bf(acc[i][j][2]+bias); v[3]=f2bf(acc[i][j][3]+bias);
        *(bf16x4*)&ob[srow] = v;
      }
    }
  }
}

// ---------------------------------------------------------------- attention
// grid (32 q-tiles of 64 rows, 64 heads), 256 threads; wave w owns q-rows w*16..+15.
// Swapped QK^T: mfma(A=K, B=Q) -> S^T[key][q]; lane (g,c) holds q = w*16+c for ALL its
// 16 score values => online softmax state (m,l) is lane-local, reduce = 2x shfl_xor.
__global__ __launch_bounds__(256)
void attn_fwd(const short* __restrict__ Qo, const short* __restrict__ Ko,
              const short* __restrict__ Vto, float* __restrict__ out)
{
  const int h  = blockIdx.y;
  const int q0 = blockIdx.x * 64;
  const int tid = threadIdx.x, lane = tid & 63, w = tid >> 6;
  const int g = lane >> 4, c = lane & 15;

  __shared__ short Ql[64 * 104];   // pitch 104 bf16 = 208B (13x16B) -> 2-way banks
  __shared__ short Kl[64 * 104];
  __shared__ short Vl[96 * 72];    // Vt tile [d][key], pitch 72
  __shared__ short Pl[64 * 72];    // P [q][key], pitch 72

  const short* __restrict__ Qh = Qo  + (size_t)h * SEQ * DHD;
  const short* __restrict__ Kh = Ko  + (size_t)h * SEQ * DHD;
  const short* __restrict__ Vh = Vto + (size_t)h * DHD * SEQ;

  // stage Q tile (64 x 96 bf16 = 768 x 16B)
#pragma unroll
  for (int j = 0; j < 3; ++j) {
    int i = tid + j * 256;
    int row = i / 12, cb = (i % 12) * 8;
    *(int4*)&Ql[row * 104 + cb] = *(const int4*)(Qh + (size_t)(q0 + row) * DHD + cb);
  }
  __syncthreads();

  // hoist Q B-fragments (reused every kv tile)
  bf16x8 qf[3];
#pragma unroll
  for (int dc = 0; dc < 3; ++dc)
    qf[dc] = *(bf16x8*)&Ql[(w*16 + c) * 104 + dc*32 + g*8];

  f32x4 octx[6];
#pragma unroll
  for (int i = 0; i < 6; ++i) octx[i] = (f32x4)0.f;
  float mrun = -__builtin_inff();
  float lrun = 0.f;
  const float rs = 0.10206207261596577f;   // 1/sqrt(96)

  for (int kv = 0; kv < SEQ/64; ++kv) {
    const int s0 = kv * 64;
    // issue K/Vt tile loads into regs before the barrier (latency overlap)
    int4 kreg[3], vreg[3];
#pragma unroll
    for (int j = 0; j < 3; ++j) {
      int i = tid + j * 256;
      int krow = i / 12, kcb = (i % 12) * 8;
      kreg[j] = *(const int4*)(Kh + (size_t)(s0 + krow) * DHD + kcb);
      int vrow = i >> 3, vcb = (i & 7) * 8;
      vreg[j] = *(const int4*)(Vh + (size_t)vrow * SEQ + s0 + vcb);
    }
    __syncthreads();                       // prev tile's consumers done
#pragma unroll
    for (int j = 0; j < 3; ++j) {
      int i = tid + j * 256;
      int krow = i / 12, kcb = (i % 12) * 8;
      *(int4*)&Kl[krow * 104 + kcb] = kreg[j];
      int vrow = i >> 3, vcb = (i & 7) * 8;
      *(int4*)&Vl[vrow * 72 + vcb] = vreg[j];
    }
    __syncthreads();

    // QK^T (swapped): sc[kt] = S^T tile, rows key=kt*16+g*4+r, col q=w*16+c
    f32x4 sc[4];
#pragma unroll
    for (int kt = 0; kt < 4; ++kt) {
      sc[kt] = (f32x4)0.f;
#pragma unroll
      for (int dc = 0; dc < 3; ++dc) {
        bf16x8 kf = *(bf16x8*)&Kl[(kt*16 + c) * 104 + dc*32 + g*8];
        sc[kt] = __builtin_amdgcn_mfma_f32_16x16x32_bf16(kf, qf[dc], sc[kt], 0, 0, 0);
      }
    }

    // online softmax over this tile's 64 keys (per q = per lane-column)
    float tmax = -__builtin_inff();
#pragma unroll
    for (int kt = 0; kt < 4; ++kt)
#pragma unroll
      for (int r = 0; r < 4; ++r) { sc[kt][r] *= rs; tmax = fmaxf(tmax, sc[kt][r]); }
    tmax = fmaxf(tmax, __shfl_xor(tmax, 16));
    tmax = fmaxf(tmax, __shfl_xor(tmax, 32));
    float mnew = fmaxf(mrun, tmax);
    float cs = __expf(mrun - mnew);
    float p[4][4];
    float psum = 0.f;
#pragma unroll
    for (int kt = 0; kt < 4; ++kt)
#pragma unroll
      for (int r = 0; r < 4; ++r) { p[kt][r] = __expf(sc[kt][r] - mnew); psum += p[kt][r]; }
    psum += __shfl_xor(psum, 16);
    psum += __shfl_xor(psum, 32);
    lrun = lrun * cs + psum;
    mrun = mnew;

    // rescale ctx acc: rows of PV C-layout are q = w*16 + g*4 + r -> fetch cs per row
    float csr[4];
#pragma unroll
    for (int r = 0; r < 4; ++r) csr[r] = __shfl(cs, g*4 + r, 64);
#pragma unroll
    for (int dt = 0; dt < 6; ++dt)
#pragma unroll
      for (int r = 0; r < 4; ++r) octx[dt][r] *= csr[r];

    // P -> LDS [q][key] (4 consecutive keys per reg group -> b64 writes)
#pragma unroll
    for (int kt = 0; kt < 4; ++kt) {
      bf16x4 pv;
      pv[0]=f2bf(p[kt][0]); pv[1]=f2bf(p[kt][1]); pv[2]=f2bf(p[kt][2]); pv[3]=f2bf(p[kt][3]);
      *(bf16x4*)&Pl[(w*16 + c) * 72 + kt*16 + g*4] = pv;
    }
    asm volatile("s_waitcnt lgkmcnt(0)" ::: "memory");

    // PV: octx[q][d] += P[q][key] V[key][d]; A=P rows q, B from Vt[d][key] (k-contig)
    bf16x8 pa[2];
#pragma unroll
    for (int kh = 0; kh < 2; ++kh)
      pa[kh] = *(bf16x8*)&Pl[(w*16 + c) * 72 + kh*32 + g*8];
#pragma unroll
    for (int dt = 0; dt < 6; ++dt)
#pragma unroll
      for (int kh = 0; kh < 2; ++kh) {
        bf16x8 vf = *(bf16x8*)&Vl[(dt*16 + c) * 72 + kh*32 + g*8];
        octx[dt] = __builtin_amdgcn_mfma_f32_16x16x32_bf16(pa[kh], vf, octx[dt], 0, 0, 0);
      }
  }

  // epilogue: divide by softmax denom, write fp32 out[s][h*96+d]
  float rl = 1.f / lrun;
  float rlr[4];
#pragma unroll
  for (int r = 0; r < 4; ++r) rlr[r] = __shfl(rl, g*4 + r, 64);
#pragma unroll
  for (int dt = 0; dt < 6; ++dt) {
    int d = dt*16 + c;
#pragma unroll
    for (int r = 0; r < 4; ++r) {
      int srow = q0 + w*16 + g*4 + r;
      out[(size_t)srow * DM + h * DHD + d] = octx[dt][r] * rlr[r];
    }
  }
}

// ---------------------------------------------------------------- launcher
extern "C" void kernel_launch(void* const* d_in, const int* in_sizes, int n_in,
                              void* d_out, int out_size, void* d_ws, size_t ws_size,
                              hipStream_t stream) {
  const float* hs = (const float*)d_in[0];
  const float* Wq = (const float*)d_in[1];
  const float* bq = (const float*)d_in[2];
  const float* Wk = (const float*)d_in[3];
  const float* bk = (const float*)d_in[4];
  const float* Wv = (const float*)d_in[5];
  const float* bv = (const float*)d_in[6];

  short* Qo = (short*)d_ws;                       // [64][2048][96] bf16
  short* Ko = Qo + (size_t)NH * SEQ * DHD;        // [64][2048][96] bf16
  short* Vt = Ko + (size_t)NH * SEQ * DHD;        // [64][96][2048] bf16
  // total workspace use: 3 * 12.58M * 2B = 75.5 MB

  qkv_gemm<<<dim3(48, 16, 3), 256, 0, stream>>>(hs, Wq, bq, Wk, bk, Wv, bv, Qo, Ko, Vt);
  attn_fwd<<<dim3(SEQ/64, NH), 256, 0, stream>>>(Qo, Ko, Vt, (float*)d_out);
}

// Round 5
// 1643.482 us; speedup vs baseline: 1.0471x; 1.0471x over previous
//
#include <hip/hip_runtime.h>
#include <hip/hip_bf16.h>
#include <stdint.h>

// SelfAttention on MI355X. Pipeline:
//   conv_bf16: hs fp32 -> Abf bf16 [2048][6144]
//   conv_wt  : W [K][N] fp32 -> Wt [N-slice][K] bf16 (transposed, bf16)
//   qkv_gemm : m97-structure 128x128x64 bf16 GEMM, 8 waves (32x64 each),
//              global_load_lds(16B), linear LDS, 2-barrier K-loop.
//              Epilogue: +bias, scatter to Q/K [h][s][d] or Vt [h][d][s].
//   attn_fwd : flash attn, 4 waves x 16 q-rows, 64-key tiles, swapped QK^T
//              (lane-local softmax state), deep prefetch, defer-max (THR=8),
//              setprio around MFMA, XCD-chunked block swizzle.
// R3/R4 bug (bit-identical absmax 5.295e-2 both rounds): conv_wt wrote int4
// (8 shorts) at a 16-short stride -> half of W^T never written. Fixed: 2 stores.

#define NH  64
#define DHD 96
#define DM  6144
#define SEQ 2048

typedef __attribute__((ext_vector_type(4))) float f4;
typedef __attribute__((ext_vector_type(4))) float f32x4;
typedef __attribute__((ext_vector_type(8))) short bf16x8;
typedef __attribute__((ext_vector_type(4))) short bf16x4;

#define GLB(p) ((const __attribute__((address_space(1))) void*)(p))
#define LDSP(p) ((__attribute__((address_space(3))) void*)(p))

static __device__ __forceinline__ short f2bf(float f) {
  unsigned int u = __builtin_bit_cast(unsigned int, f);
  u = (u + 0x7fffu + ((u >> 16) & 1u)) >> 16;   // RNE
  return (short)u;
}

// ---------------------------------------------------------------- fp32 -> bf16 (hs)
__global__ __launch_bounds__(256)
void conv_bf16(const float* __restrict__ in, short* __restrict__ out, int n8)
{
  int stride = gridDim.x * 256;
  for (int i = blockIdx.x * 256 + threadIdx.x; i < n8; i += stride) {
    f4 a = *(const f4*)(in + (size_t)i * 8);
    f4 b = *(const f4*)(in + (size_t)i * 8 + 4);
    bf16x8 v;
    v[0]=f2bf(a[0]); v[1]=f2bf(a[1]); v[2]=f2bf(a[2]); v[3]=f2bf(a[3]);
    v[4]=f2bf(b[0]); v[5]=f2bf(b[1]); v[6]=f2bf(b[2]); v[7]=f2bf(b[3]);
    *(bf16x8*)(out + (size_t)i * 8) = v;
  }
}

// -------------------------------------------- W cols [n_base, n_base+64*gridDim.x)
// fp32 [K][N] -> Wt [n_local][K] bf16; 64x64 tile per block via LDS (pitch 72 = 9x16B).
__global__ __launch_bounds__(256)
void conv_wt(const float* __restrict__ W, short* __restrict__ Wt, int n_base)
{
  __shared__ short T[64 * 72];
  const int n0 = blockIdx.x * 64, k0 = blockIdx.y * 64;
  const int t = threadIdx.x;
  const int rr = t >> 4;            // 0..15
  const int cc = (t & 15) * 4;      // 0..60 (floats)
#pragma unroll
  for (int p = 0; p < 4; ++p) {
    int r = rr + p * 16;            // k-row within tile
    f4 a = *(const f4*)(W + (size_t)(k0 + r) * DM + n_base + n0 + cc);
    T[(cc+0) * 72 + r] = f2bf(a[0]);
    T[(cc+1) * 72 + r] = f2bf(a[1]);
    T[(cc+2) * 72 + r] = f2bf(a[2]);
    T[(cc+3) * 72 + r] = f2bf(a[3]);
  }
  __syncthreads();
  const int n  = t >> 2;            // 0..63
  const int kq = (t & 3) * 16;      // shorts; thread covers 16 shorts = 2x int4
  *(int4*)(Wt + (size_t)(n0 + n) * DM + k0 + kq)     = *(const int4*)&T[n * 72 + kq];
  *(int4*)(Wt + (size_t)(n0 + n) * DM + k0 + kq + 8) = *(const int4*)&T[n * 72 + kq + 8];
}

// ---------------------------------------------------------------- QKV GEMM
// 512 thr = 8 waves (4x2 grid, 32m x 64n each), 128x128 tile, BK=64.
// LDS A[128][64] B[128][64] bf16 linear; stage: 4 global_load_lds(16B)/thread/K-step.
__global__ __launch_bounds__(512)
void qkv_gemm(const short* __restrict__ Abf, const short* __restrict__ Bt,
              const float* __restrict__ bp,
              short* __restrict__ outQK, short* __restrict__ outVt, int isV, int n_base)
{
  const int tid  = threadIdx.x;
  const int lane = tid & 63;
  const int w    = tid >> 6;                    // 0..7
  const int wr   = w >> 1, wc = w & 1;          // 4x2 wave grid
  const int g    = lane >> 4, c = lane & 15;
  const int m0   = blockIdx.y * 128;
  const int n0l  = blockIdx.x * 128;            // local col within Bt slice

  __shared__ short Al[128 * 64];
  __shared__ short Bl[128 * 64];

  f32x4 acc[2][4];
#pragma unroll
  for (int i = 0; i < 2; ++i)
#pragma unroll
    for (int j = 0; j < 4; ++j) acc[i][j] = (f32x4)0.f;

  // staging: chunk (i*64+w*8) rows; lane -> row +(lane>>3), 16B col chunk (lane&7)
  const int cr   = lane >> 3;
  const int ccol = (lane & 7) * 8;              // shorts
  const short* As = Abf + (size_t)(m0  + w*8 + cr) * DM + ccol;
  const short* Bs = Bt  + (size_t)(n0l + w*8 + cr) * DM + ccol;
  short* Adst = Al + w * 512;                   // +i*4096 shorts per instr (wave-uniform)
  short* Bdst = Bl + w * 512;

  for (int kt = 0; kt < DM / 64; ++kt) {
    const int ko = kt * 64;
#pragma unroll
    for (int i = 0; i < 2; ++i) {
      __builtin_amdgcn_global_load_lds(GLB(As + (size_t)i * 64 * DM + ko), LDSP(Adst + i * 4096), 16, 0, 0);
      __builtin_amdgcn_global_load_lds(GLB(Bs + (size_t)i * 64 * DM + ko), LDSP(Bdst + i * 4096), 16, 0, 0);
    }
    __syncthreads();   // drains vmcnt -> staged tiles visible

#pragma unroll
    for (int kh = 0; kh < 2; ++kh) {
      bf16x8 af[2], bfr[4];
#pragma unroll
      for (int i = 0; i < 2; ++i)
        af[i]  = *(const bf16x8*)&Al[(wr*32 + i*16 + c) * 64 + kh*32 + g*8];
#pragma unroll
      for (int j = 0; j < 4; ++j)
        bfr[j] = *(const bf16x8*)&Bl[(wc*64 + j*16 + c) * 64 + kh*32 + g*8];
#pragma unroll
      for (int i = 0; i < 2; ++i)
#pragma unroll
        for (int j = 0; j < 4; ++j)
          acc[i][j] = __builtin_amdgcn_mfma_f32_16x16x32_bf16(af[i], bfr[j], acc[i][j], 0, 0, 0);
    }
    __syncthreads();   // compute done before next stage overwrites
  }

  // epilogue: +bias, cast bf16. C/D: col = lane&15, row = (lane>>4)*4 + reg.
  if (!isV) {
#pragma unroll
    for (int j = 0; j < 4; ++j) {
      int n = n_base + n0l + wc*64 + j*16 + c;
      int hh = n / DHD, d = n - hh * DHD;
      float bias = bp[n];
      short* ob = outQK + (size_t)hh * SEQ * DHD + d;
#pragma unroll
      for (int i = 0; i < 2; ++i) {
        int srw = m0 + wr*32 + i*16 + g*4;
#pragma unroll
        for (int r = 0; r < 4; ++r)
          ob[(size_t)(srw + r) * DHD] = f2bf(acc[i][j][r] + bias);
      }
    }
  } else {
#pragma unroll
    for (int j = 0; j < 4; ++j) {
      int n = n_base + n0l + wc*64 + j*16 + c;
      int hh = n / DHD, d = n - hh * DHD;
      float bias = bp[n];
      short* ob = outVt + ((size_t)hh * DHD + d) * SEQ;
#pragma unroll
      for (int i = 0; i < 2; ++i) {
        int srw = m0 + wr*32 + i*16 + g*4;
        bf16x4 v;
        v[0]=f2bf(acc[i][j][0]+bias); v[1]=f2bf(acc[i][j][1]+bias);
        v[2]=f2bf(acc[i][j][2]+bias); v[3]=f2bf(acc[i][j][3]+bias);
        *(bf16x4*)&ob[srw] = v;
      }
    }
  }
}

// ---------------------------------------------------------------- attention
__global__ __launch_bounds__(256)
void attn_fwd(const short* __restrict__ Qo, const short* __restrict__ Ko,
              const short* __restrict__ Vto, float* __restrict__ out)
{
  // XCD-chunked swizzle: 2048 blocks, 8 XCDs -> each XCD gets 256 consecutive
  // logical blocks = 8 whole heads (K/V L2 locality). 2048 % 8 == 0 -> bijective.
  const int b   = blockIdx.x;
  const int swz = (b & 7) * (2048 / 8) + (b >> 3);
  const int h   = swz >> 5;
  const int q0  = (swz & 31) * 64;
  const int tid = threadIdx.x, lane = tid & 63, w = tid >> 6;
  const int g = lane >> 4, c = lane & 15;

  __shared__ short Ql[64 * 104];   // pitch 104 = 13x16B -> conflict-light
  __shared__ short Kl[64 * 104];
  __shared__ short Vl[96 * 72];    // Vt tile [d][key], pitch 72 = 9x16B
  __shared__ short Pl[64 * 72];    // P [q][key], wave-private rows

  const short* __restrict__ Qh = Qo  + (size_t)h * SEQ * DHD;
  const short* __restrict__ Kh = Ko  + (size_t)h * SEQ * DHD;
  const short* __restrict__ Vh = Vto + (size_t)h * DHD * SEQ;

  // stage Q tile
#pragma unroll
  for (int j = 0; j < 3; ++j) {
    int i = tid + j * 256;
    int row = i / 12, cb = (i % 12) * 8;
    *(int4*)&Ql[row * 104 + cb] = *(const int4*)(Qh + (size_t)(q0 + row) * DHD + cb);
  }
  __syncthreads();

  bf16x8 qf[3];
#pragma unroll
  for (int dc = 0; dc < 3; ++dc)
    qf[dc] = *(const bf16x8*)&Ql[(w*16 + c) * 104 + dc*32 + g*8];

  f32x4 octx[6];
#pragma unroll
  for (int i = 0; i < 6; ++i) octx[i] = (f32x4)0.f;
  float mrun = -__builtin_inff();
  float lrun = 0.f;
  const float rs = 0.10206207261596577f;   // 1/sqrt(96)

  // deep prefetch: tile t+1's global loads issue right after tile t's LDS writes.
  int4 kreg[3], vreg[3];
#pragma unroll
  for (int j = 0; j < 3; ++j) {
    int i = tid + j * 256;
    int krow = i / 12, kcb = (i % 12) * 8;
    kreg[j] = *(const int4*)(Kh + (size_t)krow * DHD + kcb);
    int vrow = i >> 3, vcb = (i & 7) * 8;
    vreg[j] = *(const int4*)(Vh + (size_t)vrow * SEQ + vcb);
  }

  for (int kv = 0; kv < SEQ / 64; ++kv) {
    __syncthreads();                       // all waves done reading prev K/V tiles
#pragma unroll
    for (int j = 0; j < 3; ++j) {
      int i = tid + j * 256;
      int krow = i / 12, kcb = (i % 12) * 8;
      *(int4*)&Kl[krow * 104 + kcb] = kreg[j];
      int vrow = i >> 3, vcb = (i & 7) * 8;
      *(int4*)&Vl[vrow * 72 + vcb] = vreg[j];
    }
    __syncthreads();

    if (kv + 1 < SEQ / 64) {
      const int s1 = (kv + 1) * 64;
#pragma unroll
      for (int j = 0; j < 3; ++j) {
        int i = tid + j * 256;
        int krow = i / 12, kcb = (i % 12) * 8;
        kreg[j] = *(const int4*)(Kh + (size_t)(s1 + krow) * DHD + kcb);
        int vrow = i >> 3, vcb = (i & 7) * 8;
        vreg[j] = *(const int4*)(Vh + (size_t)vrow * SEQ + s1 + vcb);
      }
    }

    // QK^T (swapped): S^T tile, row key = kt*16+g*4+r, col q = w*16+c
    f32x4 sc[4];
    __builtin_amdgcn_s_setprio(1);
#pragma unroll
    for (int kt = 0; kt < 4; ++kt) {
      sc[kt] = (f32x4)0.f;
#pragma unroll
      for (int dc = 0; dc < 3; ++dc) {
        bf16x8 kf = *(const bf16x8*)&Kl[(kt*16 + c) * 104 + dc*32 + g*8];
        sc[kt] = __builtin_amdgcn_mfma_f32_16x16x32_bf16(kf, qf[dc], sc[kt], 0, 0, 0);
      }
    }
    __builtin_amdgcn_s_setprio(0);

    // online softmax, defer-max (THR=8)
    float tmax = -__builtin_inff();
#pragma unroll
    for (int kt = 0; kt < 4; ++kt)
#pragma unroll
      for (int r = 0; r < 4; ++r) { sc[kt][r] *= rs; tmax = fmaxf(tmax, sc[kt][r]); }
    tmax = fmaxf(tmax, __shfl_xor(tmax, 16));
    tmax = fmaxf(tmax, __shfl_xor(tmax, 32));
    if (!__all(tmax - mrun <= 8.0f)) {
      float mnew = fmaxf(mrun, tmax);
      float cs = __expf(mrun - mnew);
      mrun = mnew;
      lrun *= cs;
      float csr[4];
#pragma unroll
      for (int r = 0; r < 4; ++r) csr[r] = __shfl(cs, g*4 + r, 64);
#pragma unroll
      for (int dt = 0; dt < 6; ++dt)
#pragma unroll
        for (int r = 0; r < 4; ++r) octx[dt][r] *= csr[r];
    }
    float p[4][4];
    float psum = 0.f;
#pragma unroll
    for (int kt = 0; kt < 4; ++kt)
#pragma unroll
      for (int r = 0; r < 4; ++r) { p[kt][r] = __expf(sc[kt][r] - mrun); psum += p[kt][r]; }
    psum += __shfl_xor(psum, 16);
    psum += __shfl_xor(psum, 32);
    lrun += psum;

    // P -> LDS [q][key] (wave-private rows), read back as PV A-fragments
#pragma unroll
    for (int kt = 0; kt < 4; ++kt) {
      bf16x4 pv;
      pv[0]=f2bf(p[kt][0]); pv[1]=f2bf(p[kt][1]); pv[2]=f2bf(p[kt][2]); pv[3]=f2bf(p[kt][3]);
      *(bf16x4*)&Pl[(w*16 + c) * 72 + kt*16 + g*4] = pv;
    }
    asm volatile("s_waitcnt lgkmcnt(0)" ::: "memory");
    __builtin_amdgcn_sched_barrier(0);    // rule #18

    bf16x8 pa[2];
#pragma unroll
    for (int kh = 0; kh < 2; ++kh)
      pa[kh] = *(const bf16x8*)&Pl[(w*16 + c) * 72 + kh*32 + g*8];
    __builtin_amdgcn_s_setprio(1);
#pragma unroll
    for (int dt = 0; dt < 6; ++dt)
#pragma unroll
      for (int kh = 0; kh < 2; ++kh) {
        bf16x8 vf = *(const bf16x8*)&Vl[(dt*16 + c) * 72 + kh*32 + g*8];
        octx[dt] = __builtin_amdgcn_mfma_f32_16x16x32_bf16(pa[kh], vf, octx[dt], 0, 0, 0);
      }
    __builtin_amdgcn_s_setprio(0);
  }

  float rl = 1.f / lrun;
  float rlr[4];
#pragma unroll
  for (int r = 0; r < 4; ++r) rlr[r] = __shfl(rl, g*4 + r, 64);
#pragma unroll
  for (int dt = 0; dt < 6; ++dt) {
    int d = dt*16 + c;
#pragma unroll
    for (int r = 0; r < 4; ++r) {
      int srow = q0 + w*16 + g*4 + r;
      out[(size_t)srow * DM + h * DHD + d] = octx[dt][r] * rlr[r];
    }
  }
}

// ---------------------------------------------------------------- launcher
extern "C" void kernel_launch(void* const* d_in, const int* in_sizes, int n_in,
                              void* d_out, int out_size, void* d_ws, size_t ws_size,
                              hipStream_t stream) {
  const float* hs = (const float*)d_in[0];
  const float* Ws[3] = { (const float*)d_in[1], (const float*)d_in[3], (const float*)d_in[5] };
  const float* bs[3] = { (const float*)d_in[2], (const float*)d_in[4], (const float*)d_in[6] };

  short* Qo = (short*)d_ws;                       // [64][2048][96] bf16
  short* Ko = Qo + (size_t)NH * SEQ * DHD;        // [64][2048][96] bf16
  short* Vt = Ko + (size_t)NH * SEQ * DHD;        // [64][96][2048] bf16
  short* outs[3] = { Qo, Ko, Vt };

  const size_t FULL_BYTES = 3ull*NH*SEQ*DHD*2 + (size_t)SEQ*DM*2 + (size_t)DM*DM*2; // 176,160,768

  if (ws_size >= FULL_BYTES) {
    // roomy workspace: full W^T buffer, 768-block GEMMs (3 blocks/CU)
    short* Abf = Vt  + (size_t)NH * SEQ * DHD;    // [2048][6144] bf16
    short* Wtb = Abf + (size_t)SEQ * DM;          // [6144][6144] bf16 (reused x3)
    conv_bf16<<<2048, 256, 0, stream>>>(hs, Abf, SEQ * DM / 8);
    for (int z = 0; z < 3; ++z) {
      conv_wt<<<dim3(96, 96), 256, 0, stream>>>(Ws[z], Wtb, 0);
      qkv_gemm<<<dim3(48, 16), 512, 0, stream>>>(Abf, Wtb, bs[z],
          (z < 2) ? outs[z] : nullptr, (z == 2) ? Vt : nullptr, z == 2, 0);
    }
  } else {
    // tight workspace (round-2-proven 75.5 MB in d_ws); Abf + 2048-col Wt slice
    // live in d_out (25.2 + 25.2 = 50.33 MB, exact fit); attn rewrites all of d_out.
    short* Abf = (short*)d_out;                   // [2048][6144] bf16
    short* Wts = Abf + (size_t)SEQ * DM;          // [2048][6144] bf16 slice
    conv_bf16<<<2048, 256, 0, stream>>>(hs, Abf, SEQ * DM / 8);
    for (int z = 0; z < 3; ++z)
      for (int s = 0; s < 3; ++s) {
        conv_wt<<<dim3(32, 96), 256, 0, stream>>>(Ws[z], Wts, s * 2048);
        qkv_gemm<<<dim3(16, 16), 512, 0, stream>>>(Abf, Wts, bs[z],
            (z < 2) ? outs[z] : nullptr, (z == 2) ? Vt : nullptr, z == 2, s * 2048);
      }
  }

  attn_fwd<<<2048, 256, 0, stream>>>(Qo, Ko, Vt, (float*)d_out);
}